// Round 8
// baseline (207.111 us; speedup 1.0000x reference)
//
#include <hip/hip_runtime.h>
#include <hip/hip_bf16.h>

// Round 23: r22's 3-ring counted-vmcnt schedule (proven correct, conflicts=0,
// best per-CU throughput yet) shrunk from 256^2/96KB/1blk-per-CU to
// 128^2/48KB/3blk-per-CU. r22 analysis: per-active-CU ~1008 TF-equiv but 70%
// grid fill (180 blk) wasted 30%. 128^2 gives 720 blocks on 768 resident
// slots (94% fill) + inter-block wave overlap (m114) on top of the intra-block
// pipeline. Same ledger: stage t+2 -> buf (t+2)%3 (disjoint from read bufs t,
// t+1; WAR ordered by end-of-(t-1) barrier); end-of-t vmcnt(4) retires stage
// t+1 (in-order). Same packed-pair layout (two rows share a 128B super-row,
// swizzle pos^((row>>1)&3) -> all 8 bank groups). Rest = r22.
//
// ws layout (r10):
//   [A] qkv_b16: 3072*3840 bf16   [B] hs_b: 3072*1280 bf16 (-> attn_b)
//   [C] qkvw_b : 3840*1280 bf16 (-> Qp)   [D] projw_b: 1280*1280 bf16
//   [E] Kp 9.4MB   [F] Vp 9.4MB (96-wide, col80 = ones)

#define S_TOT 3072
#define DIM   1280
#define NH    16
#define HD    80
#define SEG   1024
#define TDIM  3840
#define K1    1280

typedef short v8s __attribute__((ext_vector_type(8)));
typedef float v4f __attribute__((ext_vector_type(4)));

__device__ __forceinline__ short f2bf(float v) {
  __hip_bfloat16 b = __float2bfloat16(v);
  return *reinterpret_cast<short*>(&b);
}

__device__ __forceinline__ float bf2f(short s) {
  unsigned u = ((unsigned)(unsigned short)s) << 16;
  float f;
  __builtin_memcpy(&f, &u, 4);
  return f;
}

// async global->LDS, 16B per lane, wave-uniform LDS base + lane*16 dest
__device__ __forceinline__ void gload16(const void* g, void* lds) {
  __builtin_amdgcn_global_load_lds(
      (const __attribute__((address_space(1))) char*)g,
      (__attribute__((address_space(3))) char*)lds, 16, 0, 0);
}

#define CVT_N1 (S_TOT * DIM / 4)
#define CVT_N2 (TDIM * DIM / 4)
#define CVT_N3 (DIM * DIM / 4)
__global__ __launch_bounds__(256) void cvt3(const float* __restrict__ in1,
                                            const float* __restrict__ in2,
                                            const float* __restrict__ in3,
                                            __hip_bfloat16* __restrict__ o1,
                                            __hip_bfloat16* __restrict__ o2,
                                            __hip_bfloat16* __restrict__ o3) {
  int i = blockIdx.x * 256 + threadIdx.x;
  const float* in;
  __hip_bfloat16* out;
  if (i < CVT_N1) { in = in1; out = o1; }
  else if (i < CVT_N1 + CVT_N2) { in = in2; out = o2; i -= CVT_N1; }
  else { in = in3; out = o3; i -= CVT_N1 + CVT_N2; }
  const float4 v = ((const float4*)in)[i];
  __hip_bfloat162 p0, p1;
  p0.x = __float2bfloat16(v.x); p0.y = __float2bfloat16(v.y);
  p1.x = __float2bfloat16(v.z); p1.y = __float2bfloat16(v.w);
  __hip_bfloat162* o = (__hip_bfloat162*)(out + (size_t)i * 4);
  o[0] = p0; o[1] = p1;
}

// ===== gemm1_3r: 128x128, BK=32, 3-ring (48KB), counted vmcnt, 3 blk/CU =====
// LDS buffer b at b*8192 shorts: A region +0 (128 rows), B region +4096.
// Chunk (row,pos): offset (row>>1)*64 + (row&1)*32 + pos*8 shorts; holds
// global k-chunk pos ^ ((row>>1)&3). Staged linearly: chunk ci = c*256 + tid.
extern __shared__ short ring[];

__global__ __launch_bounds__(256, 3) void gemm1_3r(const __hip_bfloat16* __restrict__ A,
                                                   const __hip_bfloat16* __restrict__ B,
                                                   const float* __restrict__ bias,
                                                   __hip_bfloat16* __restrict__ C) {
  const int tid  = threadIdx.x;
  const int wave = tid >> 6;
  const int lane = tid & 63;
  const int quad = lane >> 4;
  const int l16  = lane & 15;
  const int wmp  = wave >> 1;        // 0..1 : wave M-half (64 rows)
  const int wnp  = wave & 1;         // 0..1 : wave N-half (64 cols)
  const int bm = blockIdx.x * 128;
  const int bn = blockIdx.y * 128;

  // ---- staging source (src-side pre-swizzle; thread's chunks = tid, 256+tid)
  const int r0 = ((tid >> 3) << 1) + ((tid >> 2) & 1);   // row 0..63
  const int gs = (tid & 3) ^ ((tid >> 3) & 3);           // source k-chunk
  const short* A0 = (const short*)A + (size_t)(bm + r0) * K1 + gs * 8;
  const short* A1 = A0 + (size_t)64 * K1;
  const short* B0 = (const short*)B + (size_t)(bn + r0) * K1 + gs * 8;
  const short* B1 = B0 + (size_t)64 * K1;
  const int wst = wave * 512;        // wave-uniform LDS offset (shorts)

#define STG(sbuf, ko) do {                              \
    short* d_ = ring + (sbuf) * 8192;                   \
    gload16(A0 + (ko), d_ + wst);                       \
    gload16(A1 + (ko), d_ + 2048 + wst);                \
    gload16(B0 + (ko), d_ + 4096 + wst);                \
    gload16(B1 + (ko), d_ + 6144 + wst);                \
  } while (0)

  // ---- read-side bases (per-thread constants) ----
  const int posA  = quad ^ ((l16 >> 1) & 3);
  const int rbase = (l16 >> 1) * 64 + (l16 & 1) * 32 + posA * 8;
  const int Abase = wmp * 2048 + rbase;          // + i*512 per 16-row step
  const int Bbase = 4096 + wnp * 2048 + rbase;   // + j*512

  v4f acc[4][4];
  const v4f vz = {0.f, 0.f, 0.f, 0.f};
  #pragma unroll
  for (int i = 0; i < 4; ++i)
    #pragma unroll
    for (int j = 0; j < 4; ++j) acc[i][j] = vz;

  // ---- prologue: stage tiles 0,1; wait for tile 0 only (counted) ----
  STG(0, 0);
  STG(1, 32);
  asm volatile("s_waitcnt vmcnt(4)" ::: "memory");
  __builtin_amdgcn_s_barrier();
  __builtin_amdgcn_sched_barrier(0);

  int cb = 0, sb = 2;                // read buf, stage buf
  for (int t = 0; t < 40; ++t) {
    if (t + 2 < 40) STG(sb, (t + 2) * 32);

    const short* lb = ring + cb * 8192;
    v8s af[4], bf[4];
    #pragma unroll
    for (int i = 0; i < 4; ++i) af[i] = *(const v8s*)&lb[Abase + i * 512];
    #pragma unroll
    for (int j = 0; j < 4; ++j) bf[j] = *(const v8s*)&lb[Bbase + j * 512];

    __builtin_amdgcn_s_setprio(1);
    #pragma unroll
    for (int i = 0; i < 4; ++i)
      #pragma unroll
      for (int j = 0; j < 4; ++j)
        acc[i][j] = __builtin_amdgcn_mfma_f32_16x16x32_bf16(af[i], bf[j], acc[i][j], 0, 0, 0);
    __builtin_amdgcn_s_setprio(0);

    if (t < 39) {
      if (t + 2 < 40) asm volatile("s_waitcnt vmcnt(4)" ::: "memory");
      else            asm volatile("s_waitcnt vmcnt(0)" ::: "memory");
      __builtin_amdgcn_s_barrier();
      __builtin_amdgcn_sched_barrier(0);
    }
    cb = (cb == 2) ? 0 : cb + 1;
    sb = (sb == 2) ? 0 : sb + 1;
  }
#undef STG

  #pragma unroll
  for (int j = 0; j < 4; ++j) {
    const int col = bn + wnp * 64 + j * 16 + l16;
    const float bj = bias[col];
    #pragma unroll
    for (int i = 0; i < 4; ++i) {
      const int row0 = bm + wmp * 64 + i * 16 + quad * 4;
      #pragma unroll
      for (int r = 0; r < 4; ++r)
        C[(size_t)(row0 + r) * TDIM + col] = __float2bfloat16(acc[i][j][r] + bj);
    }
  }
}

// ---------------- gemm2: 64x128, BK=64, r15 reg-staged + XOR swizzle ----------
__global__ __launch_bounds__(256) void gemm2_c(const __hip_bfloat16* __restrict__ A,
                                               const __hip_bfloat16* __restrict__ B,
                                               const float* __restrict__ bias,
                                               float* __restrict__ C,
                                               int M, int N, int K) {
  __shared__ __align__(16) short Abuf[2][4096];  // 8 KB each
  __shared__ __align__(16) short Bbuf[2][8192];  // 16 KB each
  const int tid  = threadIdx.x;
  const int wave = tid >> 6;
  const int lane = tid & 63;
  const int quad = lane >> 4;
  const int l16  = lane & 15;
  const int bm = blockIdx.x * 64;    // M fastest
  const int bn = blockIdx.y * 128;
  const int wm = (wave & 1) * 32;
  const int wn = (wave >> 1) * 64;

  const int srow = tid >> 3;
  const int skh  = tid & 7;
  const __hip_bfloat16* Ag[2];
  const __hip_bfloat16* Bg[4];
  int Ao[2], Bo[4];
  #pragma unroll
  for (int l = 0; l < 2; ++l) {
    const int row = l * 32 + srow;
    Ag[l] = A + (size_t)(bm + row) * K + skh * 8;
    Ao[l] = (row * 8 + (skh ^ (row & 7))) * 8;
  }
  #pragma unroll
  for (int l = 0; l < 4; ++l) {
    const int row = l * 32 + srow;
    Bg[l] = B + (size_t)(bn + row) * K + skh * 8;
    Bo[l] = (row * 8 + (skh ^ (row & 7))) * 8;
  }

  v4f acc[2][4];
  const v4f vz = {0.f, 0.f, 0.f, 0.f};
  #pragma unroll
  for (int i = 0; i < 2; ++i)
    #pragma unroll
    for (int j = 0; j < 4; ++j) acc[i][j] = vz;

  const int sw = l16 & 7;
  const int nk = K >> 6;
  v8s ra[2], rb[4];

  #pragma unroll
  for (int l = 0; l < 2; ++l) ra[l] = *(const v8s*)Ag[l];
  #pragma unroll
  for (int l = 0; l < 4; ++l) rb[l] = *(const v8s*)Bg[l];
  #pragma unroll
  for (int l = 0; l < 2; ++l) *(v8s*)&Abuf[0][Ao[l]] = ra[l];
  #pragma unroll
  for (int l = 0; l < 4; ++l) *(v8s*)&Bbuf[0][Bo[l]] = rb[l];
  __syncthreads();

  for (int k = 0; k < nk; ++k) {
    const int cur = k & 1;
    const bool more = (k + 1 < nk);
    if (more) {
      const int off = (k + 1) * 64;
      #pragma unroll
      for (int l = 0; l < 2; ++l) ra[l] = *(const v8s*)(Ag[l] + off);
      #pragma unroll
      for (int l = 0; l < 4; ++l) rb[l] = *(const v8s*)(Bg[l] + off);
    }
    #pragma unroll
    for (int s = 0; s < 2; ++s) {
      const int khx = (s * 4 + quad) ^ sw;
      v8s af[2], bf[4];
      #pragma unroll
      for (int i = 0; i < 2; ++i)
        af[i] = *(const v8s*)&Abuf[cur][((wm + i * 16 + l16) * 8 + khx) * 8];
      #pragma unroll
      for (int j = 0; j < 4; ++j)
        bf[j] = *(const v8s*)&Bbuf[cur][((wn + j * 16 + l16) * 8 + khx) * 8];
      #pragma unroll
      for (int i = 0; i < 2; ++i)
        #pragma unroll
        for (int j = 0; j < 4; ++j)
          acc[i][j] = __builtin_amdgcn_mfma_f32_16x16x32_bf16(af[i], bf[j], acc[i][j], 0, 0, 0);
    }
    if (more) {
      #pragma unroll
      for (int l = 0; l < 2; ++l) *(v8s*)&Abuf[1 - cur][Ao[l]] = ra[l];
      #pragma unroll
      for (int l = 0; l < 4; ++l) *(v8s*)&Bbuf[1 - cur][Bo[l]] = rb[l];
    }
    __syncthreads();
  }

  #pragma unroll
  for (int j = 0; j < 4; ++j) {
    const int col = bn + wn + j * 16 + l16;
    const float bj = bias[col];
    #pragma unroll
    for (int i = 0; i < 2; ++i) {
      const int row0 = bm + wm + i * 16 + quad * 4;
      #pragma unroll
      for (int r = 0; r < 4; ++r)
        C[(size_t)(row0 + r) * N + col] = acc[i][j][r] + bj;
    }
  }
}

// ---------------- merged pack kernel (unchanged) ----------------
#define QK_BLOCKS ((2 * S_TOT * 16 * 12) / 256)   // 4608
#define V_BLOCKS  ((3 * 16 * 16 * 8 * 96) / 256)  // 2304
__global__ __launch_bounds__(256) void pack_all(const __hip_bfloat16* __restrict__ qkv,
                                                const float* __restrict__ cos_,
                                                const float* __restrict__ sin_,
                                                short* __restrict__ Qp,
                                                short* __restrict__ Kp,
                                                short* __restrict__ Vp) {
  const int bid = blockIdx.x;
  if (bid < QK_BLOCKS) {
    const int idx = bid * 256 + threadIdx.x;
    const int kd = idx % 12;
    const int h  = (idx / 12) % 16;
    const int s  = (idx / 192) % S_TOT;
    const int p  = idx / (192 * S_TOT);
    const int seg = s >> 10, tb = (s >> 6) & 15, t = s & 63;
    short* out = (p ? Kp : Qp) +
                 ((size_t)(((seg * 16 + h) * 16 + tb) * 12 + kd) * 64 + t) * 8;
    short tmp[8];
    if (kd >= 10) {
      #pragma unroll
      for (int j = 0; j < 8; ++j) tmp[j] = 0;
      *(int4*)out = *(int4*)tmp;
      return;
    }
    const short* row = (const short*)qkv + (size_t)s * TDIM + p * DIM + h * HD;
    const int d0 = kd * 8;
    const v8s xm = *(const v8s*)(row + d0);
    const v8s xr = *(const v8s*)(row + d0 + ((kd < 5) ? 40 : -40));
    const float sgn = (kd < 5) ? -1.f : 1.f;
    const float scale = (p == 0) ? 0.111803398874989485f : 1.0f;
    #pragma unroll
    for (int j = 0; j < 8; ++j) {
      const int d = d0 + j;
      const float v = (bf2f(xm[j]) * cos_[s * HD + d] +
                       sgn * bf2f(xr[j]) * sin_[s * HD + d]) * scale;
      tmp[j] = f2bf(v);
    }
    *(int4*)out = *(int4*)tmp;
  } else {
    const int idx = (bid - QK_BLOCKS) * 256 + threadIdx.x;
    const int d  = idx % 96;
    const int td = (idx / 96) % 8;
    const int tb = (idx / 768) % 16;
    const int h  = (idx / (768 * 16)) % 16;
    const int seg = idx / (768 * 256);
    const int s0 = seg * SEG + tb * 64 + td * 8;
    const short* q = (const short*)qkv;
    short tmp[8];
    if (d < 80) {
      #pragma unroll
      for (int j = 0; j < 8; ++j)
        tmp[j] = q[(size_t)(s0 + j) * TDIM + 2 * DIM + h * HD + d];
    } else {
      const short fill = (d == 80) ? (short)0x3F80 : (short)0;
      #pragma unroll
      for (int j = 0; j < 8; ++j) tmp[j] = fill;
    }
    *(int4*)(Vp + (size_t)idx * 8) = *(int4*)tmp;
  }
}

// -------- fused flash MFMA attention (r19 XCD group mapping, kept) ----------
__global__ __launch_bounds__(256, 4) void attn_mfma(const short* __restrict__ Qp,
                                                    const short* __restrict__ Kp,
                                                    const short* __restrict__ Vp,
                                                    __hip_bfloat16* __restrict__ out) {
  __shared__ __align__(16) short Ks[64 * 96];
  __shared__ __align__(16) short Vs[64 * 96];
  __shared__ __align__(16) short Ps[4][16 * 68];

  const int l   = blockIdx.x;
  const int xcd = l & 7;
  const int j8  = l >> 3;            // 0..95
  const int g   = xcd * 6 + (j8 >> 4);  // group 0..47  (= seg*16 + h)
  const int qt  = j8 & 15;
  const int h   = g & 15;
  const int seg = g >> 4;
  const int tid  = threadIdx.x;
  const int wave = tid >> 6;
  const int lane = tid & 63;
  const int quad = lane >> 4;
  const int l16  = lane & 15;
  const int sh16 = g;

  const short* Qg = Qp + (size_t)(sh16 * 16 + qt) * 6144;
  const short* Kg = Kp + (size_t)sh16 * 16 * 6144;
  const short* Vg = Vp + (size_t)sh16 * 16 * 6144;

  v8s af[3];
  #pragma unroll
  for (int ks = 0; ks < 3; ++ks)
    af[ks] = *(const v8s*)(Qg + ((ks * 4 + quad) * 64 + wave * 16 + l16) * 8);

  v8s kr[3], vr[3];
  #pragma unroll
  for (int it = 0; it < 3; ++it) {
    const int o = (it * 256 + tid) * 8;
    kr[it] = *(const v8s*)(Kg + o);
    vr[it] = *(const v8s*)(Vg + o);
  }
  #pragma unroll
  for (int it = 0; it < 3; ++it) {
    const int o = (it * 256 + tid) * 8;
    *(v8s*)&Ks[o] = kr[it];
    *(v8s*)&Vs[o] = vr[it];
  }
  __syncthreads();

  v4f o4[6];
  const v4f vz = {0.f, 0.f, 0.f, 0.f};
  #pragma unroll
  for (int n = 0; n < 6; ++n) o4[n] = vz;

  for (int kb = 0; kb < 16; ++kb) {
    const bool more = (kb + 1 < 16);
    if (more) {
      const size_t base = (size_t)(kb + 1) * 6144;
      #pragma unroll
      for (int it = 0; it < 3; ++it) {
        const int o = (it * 256 + tid) * 8;
        kr[it] = *(const v8s*)(Kg + base + o);
        vr[it] = *(const v8s*)(Vg + base + o);
      }
    }

    v4f s4[4];
    #pragma unroll
    for (int j = 0; j < 4; ++j) {
      s4[j] = vz;
      #pragma unroll
      for (int ks = 0; ks < 3; ++ks) {
        const v8s bf = *(const v8s*)&Ks[((ks * 4 + quad) * 64 + j * 16 + l16) * 8];
        s4[j] = __builtin_amdgcn_mfma_f32_16x16x32_bf16(af[ks], bf, s4[j], 0, 0, 0);
      }
    }

    #pragma unroll
    for (int reg = 0; reg < 4; ++reg)
      #pragma unroll
      for (int j = 0; j < 4; ++j)
        Ps[wave][(quad * 4 + reg) * 68 + j * 16 + l16] = f2bf(__expf(s4[j][reg]));

    v8s pa[2];
    #pragma unroll
    for (int kp = 0; kp < 2; ++kp)
      pa[kp] = *(const v8s*)&Ps[wave][l16 * 68 + kp * 32 + quad * 8];
    #pragma unroll
    for (int n = 0; n < 6; ++n) {
      #pragma unroll
      for (int kp = 0; kp < 2; ++kp) {
        const v8s vb = *(const v8s*)&Vs[((kp * 4 + quad) * 96 + n * 16 + l16) * 8];
        o4[n] = __builtin_amdgcn_mfma_f32_16x16x32_bf16(pa[kp], vb, o4[n], 0, 0, 0);
      }
    }

    __syncthreads();
    if (more) {
      #pragma unroll
      for (int it = 0; it < 3; ++it) {
        const int o = (it * 256 + tid) * 8;
        *(v8s*)&Ks[o] = kr[it];
        *(v8s*)&Vs[o] = vr[it];
      }
    }
    __syncthreads();
  }

  float inv[4];
  #pragma unroll
  for (int r = 0; r < 4; ++r)
    inv[r] = 1.f / __shfl(o4[5][r], quad << 4);
  const int row0 = seg * SEG + qt * 64 + wave * 16 + quad * 4;
  #pragma unroll
  for (int n = 0; n < 5; ++n) {
    const int col = h * HD + n * 16 + l16;
    #pragma unroll
    for (int r = 0; r < 4; ++r)
      out[(size_t)(row0 + r) * DIM + col] = __float2bfloat16(o4[n][r] * inv[r]);
  }
}

extern "C" void kernel_launch(void* const* d_in, const int* in_sizes, int n_in,
                              void* d_out, int out_size, void* d_ws, size_t ws_size,
                              hipStream_t stream) {
  (void)in_sizes; (void)n_in; (void)out_size; (void)ws_size;
  const float* hs     = (const float*)d_in[0];
  const float* cosp   = (const float*)d_in[1];
  const float* sinp   = (const float*)d_in[2];
  const float* qkv_w  = (const float*)d_in[3];
  const float* qkv_b  = (const float*)d_in[4];
  const float* proj_w = (const float*)d_in[5];
  const float* proj_b = (const float*)d_in[6];

  float* out_f = (float*)d_out;
  __hip_bfloat16* qkv_b16 = (__hip_bfloat16*)d_ws;                     // [A]
  __hip_bfloat16* hs_b    = qkv_b16 + (size_t)S_TOT * TDIM;            // [B]
  __hip_bfloat16* qkvw_b  = hs_b + (size_t)S_TOT * DIM;                // [C]
  __hip_bfloat16* projw_b = qkvw_b + (size_t)TDIM * DIM;               // [D]
  short* Qp = (short*)qkvw_b;                                          // alias [C]
  short* Kp = (short*)(projw_b + (size_t)DIM * DIM);                   // [E]
  short* Vp = Kp + (size_t)3 * 16 * 16 * 6144;                         // [F]
  __hip_bfloat16* attn_b = hs_b;                                       // alias [B]

  static bool attr_set = false;
  if (!attr_set) {
    hipFuncSetAttribute((const void*)gemm1_3r,
                        hipFuncAttributeMaxDynamicSharedMemorySize, 49152);
    attr_set = true;
  }

  cvt3<<<(CVT_N1 + CVT_N2 + CVT_N3) / 256, 256, 0, stream>>>(
      hs, qkv_w, proj_w, hs_b, qkvw_b, projw_b);

  gemm1_3r<<<dim3(S_TOT / 128, TDIM / 128), 256, 49152, stream>>>(
      hs_b, qkvw_b, qkv_b, qkv_b16);

  pack_all<<<QK_BLOCKS + V_BLOCKS, 256, 0, stream>>>(qkv_b16, cosp, sinp, Qp, Kp, Vp);

  attn_mfma<<<dim3(768), 256, 0, stream>>>(Qp, Kp, Vp, attn_b);

  gemm2_c<<<dim3(S_TOT / 64, DIM / 128), 256, 0, stream>>>(
      attn_b, projw_b, proj_b, out_f, S_TOT, DIM, DIM);
}

// Round 9
// 205.798 us; speedup vs baseline: 1.0064x; 1.0064x over previous
//
#include <hip/hip_runtime.h>
#include <hip/hip_bf16.h>

// Round 24: consolidation. r23's 128^2 shrink REGRESSED gemm1 (42.6->46.6):
// smaller tile doubles staged bytes/FLOP and halves MFMA per sync. Revert
// gemm1 to r22's 256^2 3-ring (best measured, 42.6us, conflicts=0). Port the
// SAME proven 3-ring structure to gemm2 (128^2, BK=32, 48KB, 240 blocks) --
// identical K=1280 addressing, only output dtype/bias differ. Est. gemm2
// ~25 -> ~18us. attn XCD map, pack, cvt unchanged.
//
// ws layout (r10):
//   [A] qkv_b16: 3072*3840 bf16   [B] hs_b: 3072*1280 bf16 (-> attn_b)
//   [C] qkvw_b : 3840*1280 bf16 (-> Qp)   [D] projw_b: 1280*1280 bf16
//   [E] Kp 9.4MB   [F] Vp 9.4MB (96-wide, col80 = ones)

#define S_TOT 3072
#define DIM   1280
#define NH    16
#define HD    80
#define SEG   1024
#define TDIM  3840
#define K1    1280

typedef short v8s __attribute__((ext_vector_type(8)));
typedef float v4f __attribute__((ext_vector_type(4)));

__device__ __forceinline__ short f2bf(float v) {
  __hip_bfloat16 b = __float2bfloat16(v);
  return *reinterpret_cast<short*>(&b);
}

__device__ __forceinline__ float bf2f(short s) {
  unsigned u = ((unsigned)(unsigned short)s) << 16;
  float f;
  __builtin_memcpy(&f, &u, 4);
  return f;
}

// async global->LDS, 16B per lane, wave-uniform LDS base + lane*16 dest
__device__ __forceinline__ void gload16(const void* g, void* lds) {
  __builtin_amdgcn_global_load_lds(
      (const __attribute__((address_space(1))) char*)g,
      (__attribute__((address_space(3))) char*)lds, 16, 0, 0);
}

#define CVT_N1 (S_TOT * DIM / 4)
#define CVT_N2 (TDIM * DIM / 4)
#define CVT_N3 (DIM * DIM / 4)
__global__ __launch_bounds__(256) void cvt3(const float* __restrict__ in1,
                                            const float* __restrict__ in2,
                                            const float* __restrict__ in3,
                                            __hip_bfloat16* __restrict__ o1,
                                            __hip_bfloat16* __restrict__ o2,
                                            __hip_bfloat16* __restrict__ o3) {
  int i = blockIdx.x * 256 + threadIdx.x;
  const float* in;
  __hip_bfloat16* out;
  if (i < CVT_N1) { in = in1; out = o1; }
  else if (i < CVT_N1 + CVT_N2) { in = in2; out = o2; i -= CVT_N1; }
  else { in = in3; out = o3; i -= CVT_N1 + CVT_N2; }
  const float4 v = ((const float4*)in)[i];
  __hip_bfloat162 p0, p1;
  p0.x = __float2bfloat16(v.x); p0.y = __float2bfloat16(v.y);
  p1.x = __float2bfloat16(v.z); p1.y = __float2bfloat16(v.w);
  __hip_bfloat162* o = (__hip_bfloat162*)(out + (size_t)i * 4);
  o[0] = p0; o[1] = p1;
}

// ============ gemm1_3r: 256x256, BK=32, 3-ring (96KB), counted vmcnt =========
// (r22 verbatim -- measured 42.6us, conflicts 0, passed.)
// LDS buffer b at b*16384 shorts: A region +0 (256 rows), B region +8192.
// Chunk (row,pos): offset (row>>1)*64 + (row&1)*32 + pos*8 shorts; holds
// global k-chunk pos ^ ((row>>1)&3). Staged linearly: chunk ci = c*512 + tid.
extern __shared__ short ring[];

__global__ __launch_bounds__(512, 2) void gemm1_3r(const __hip_bfloat16* __restrict__ A,
                                                   const __hip_bfloat16* __restrict__ B,
                                                   const float* __restrict__ bias,
                                                   __hip_bfloat16* __restrict__ C) {
  const int tid  = threadIdx.x;
  const int wave = tid >> 6;
  const int lane = tid & 63;
  const int quad = lane >> 4;
  const int l16  = lane & 15;
  const int wmp  = wave >> 2;        // 0..1 : wave M-half (128 rows)
  const int wnp  = wave & 3;         // 0..3 : wave N-strip (64 cols)
  const int bm = blockIdx.x * 256;
  const int bn = blockIdx.y * 256;

  // ---- staging source (src-side pre-swizzle; thread's chunk = c*512 + tid) --
  const int r0 = ((tid >> 3) << 1) + ((tid >> 2) & 1);   // row 0..127 in half
  const int gs = (tid & 3) ^ ((tid >> 3) & 3);           // source k-chunk
  const short* A0 = (const short*)A + (size_t)(bm + r0) * K1 + gs * 8;
  const short* A1 = A0 + (size_t)128 * K1;
  const short* B0 = (const short*)B + (size_t)(bn + r0) * K1 + gs * 8;
  const short* B1 = B0 + (size_t)128 * K1;
  const int wst = wave * 512;        // wave-uniform LDS offset (shorts)

#define STG(sbuf, ko) do {                              \
    short* d_ = ring + (sbuf) * 16384;                  \
    gload16(A0 + (ko), d_ + wst);                       \
    gload16(A1 + (ko), d_ + 4096 + wst);                \
    gload16(B0 + (ko), d_ + 8192 + wst);                \
    gload16(B1 + (ko), d_ + 12288 + wst);               \
  } while (0)

  // ---- read-side bases (per-thread constants) ----
  const int posA  = quad ^ ((l16 >> 1) & 3);
  const int rbase = (l16 >> 1) * 64 + (l16 & 1) * 32 + posA * 8;
  const int Abase = wmp * 4096 + rbase;          // + i*512 per 16-row step
  const int Bbase = 8192 + wnp * 2048 + rbase;   // + j*512

  v4f acc[8][4];
  const v4f vz = {0.f, 0.f, 0.f, 0.f};
  #pragma unroll
  for (int i = 0; i < 8; ++i)
    #pragma unroll
    for (int j = 0; j < 4; ++j) acc[i][j] = vz;

  // ---- prologue: stage tiles 0,1; wait for tile 0 only (counted) ----
  STG(0, 0);
  STG(1, 32);
  asm volatile("s_waitcnt vmcnt(4)" ::: "memory");
  __builtin_amdgcn_s_barrier();
  __builtin_amdgcn_sched_barrier(0);

  int cb = 0, sb = 2;                // read buf, stage buf
  for (int t = 0; t < 40; ++t) {
    if (t + 2 < 40) STG(sb, (t + 2) * 32);

    const short* lb = ring + cb * 16384;
    v8s af[8], bf[4];
    #pragma unroll
    for (int i = 0; i < 8; ++i) af[i] = *(const v8s*)&lb[Abase + i * 512];
    #pragma unroll
    for (int j = 0; j < 4; ++j) bf[j] = *(const v8s*)&lb[Bbase + j * 512];

    __builtin_amdgcn_s_setprio(1);
    #pragma unroll
    for (int i = 0; i < 8; ++i)
      #pragma unroll
      for (int j = 0; j < 4; ++j)
        acc[i][j] = __builtin_amdgcn_mfma_f32_16x16x32_bf16(af[i], bf[j], acc[i][j], 0, 0, 0);
    __builtin_amdgcn_s_setprio(0);

    if (t < 39) {
      if (t + 2 < 40) asm volatile("s_waitcnt vmcnt(4)" ::: "memory");
      else            asm volatile("s_waitcnt vmcnt(0)" ::: "memory");
      __builtin_amdgcn_s_barrier();
      __builtin_amdgcn_sched_barrier(0);
    }
    cb = (cb == 2) ? 0 : cb + 1;
    sb = (sb == 2) ? 0 : sb + 1;
  }
#undef STG

  #pragma unroll
  for (int j = 0; j < 4; ++j) {
    const int col = bn + wnp * 64 + j * 16 + l16;
    const float bj = bias[col];
    #pragma unroll
    for (int i = 0; i < 8; ++i) {
      const int row0 = bm + wmp * 128 + i * 16 + quad * 4;
      #pragma unroll
      for (int r = 0; r < 4; ++r)
        C[(size_t)(row0 + r) * TDIM + col] = __float2bfloat16(acc[i][j][r] + bj);
    }
  }
}

// ===== gemm2_3r: 128x128, BK=32, 3-ring (48KB), counted vmcnt, f32 out =======
// Same structure as r23's gemm1_3r (passed refcheck); K=1280 identical.
__global__ __launch_bounds__(256, 3) void gemm2_3r(const __hip_bfloat16* __restrict__ A,
                                                   const __hip_bfloat16* __restrict__ B,
                                                   const float* __restrict__ bias,
                                                   float* __restrict__ C) {
  const int tid  = threadIdx.x;
  const int wave = tid >> 6;
  const int lane = tid & 63;
  const int quad = lane >> 4;
  const int l16  = lane & 15;
  const int wmp  = wave >> 1;        // 0..1 : wave M-half (64 rows)
  const int wnp  = wave & 1;         // 0..1 : wave N-half (64 cols)
  const int bm = blockIdx.x * 128;
  const int bn = blockIdx.y * 128;

  const int r0 = ((tid >> 3) << 1) + ((tid >> 2) & 1);   // row 0..63
  const int gs = (tid & 3) ^ ((tid >> 3) & 3);           // source k-chunk
  const short* A0 = (const short*)A + (size_t)(bm + r0) * K1 + gs * 8;
  const short* A1 = A0 + (size_t)64 * K1;
  const short* B0 = (const short*)B + (size_t)(bn + r0) * K1 + gs * 8;
  const short* B1 = B0 + (size_t)64 * K1;
  const int wst = wave * 512;

#define STG2(sbuf, ko) do {                             \
    short* d_ = ring + (sbuf) * 8192;                   \
    gload16(A0 + (ko), d_ + wst);                       \
    gload16(A1 + (ko), d_ + 2048 + wst);                \
    gload16(B0 + (ko), d_ + 4096 + wst);                \
    gload16(B1 + (ko), d_ + 6144 + wst);                \
  } while (0)

  const int posA  = quad ^ ((l16 >> 1) & 3);
  const int rbase = (l16 >> 1) * 64 + (l16 & 1) * 32 + posA * 8;
  const int Abase = wmp * 2048 + rbase;
  const int Bbase = 4096 + wnp * 2048 + rbase;

  v4f acc[4][4];
  const v4f vz = {0.f, 0.f, 0.f, 0.f};
  #pragma unroll
  for (int i = 0; i < 4; ++i)
    #pragma unroll
    for (int j = 0; j < 4; ++j) acc[i][j] = vz;

  STG2(0, 0);
  STG2(1, 32);
  asm volatile("s_waitcnt vmcnt(4)" ::: "memory");
  __builtin_amdgcn_s_barrier();
  __builtin_amdgcn_sched_barrier(0);

  int cb = 0, sb = 2;
  for (int t = 0; t < 40; ++t) {
    if (t + 2 < 40) STG2(sb, (t + 2) * 32);

    const short* lb = ring + cb * 8192;
    v8s af[4], bf[4];
    #pragma unroll
    for (int i = 0; i < 4; ++i) af[i] = *(const v8s*)&lb[Abase + i * 512];
    #pragma unroll
    for (int j = 0; j < 4; ++j) bf[j] = *(const v8s*)&lb[Bbase + j * 512];

    __builtin_amdgcn_s_setprio(1);
    #pragma unroll
    for (int i = 0; i < 4; ++i)
      #pragma unroll
      for (int j = 0; j < 4; ++j)
        acc[i][j] = __builtin_amdgcn_mfma_f32_16x16x32_bf16(af[i], bf[j], acc[i][j], 0, 0, 0);
    __builtin_amdgcn_s_setprio(0);

    if (t < 39) {
      if (t + 2 < 40) asm volatile("s_waitcnt vmcnt(4)" ::: "memory");
      else            asm volatile("s_waitcnt vmcnt(0)" ::: "memory");
      __builtin_amdgcn_s_barrier();
      __builtin_amdgcn_sched_barrier(0);
    }
    cb = (cb == 2) ? 0 : cb + 1;
    sb = (sb == 2) ? 0 : sb + 1;
  }
#undef STG2

  #pragma unroll
  for (int j = 0; j < 4; ++j) {
    const int col = bn + wnp * 64 + j * 16 + l16;
    const float bj = bias[col];
    #pragma unroll
    for (int i = 0; i < 4; ++i) {
      const int row0 = bm + wmp * 64 + i * 16 + quad * 4;
      #pragma unroll
      for (int r = 0; r < 4; ++r)
        C[(size_t)(row0 + r) * DIM + col] = acc[i][j][r] + bj;
    }
  }
}

// ---------------- merged pack kernel (unchanged) ----------------
#define QK_BLOCKS ((2 * S_TOT * 16 * 12) / 256)   // 4608
#define V_BLOCKS  ((3 * 16 * 16 * 8 * 96) / 256)  // 2304
__global__ __launch_bounds__(256) void pack_all(const __hip_bfloat16* __restrict__ qkv,
                                                const float* __restrict__ cos_,
                                                const float* __restrict__ sin_,
                                                short* __restrict__ Qp,
                                                short* __restrict__ Kp,
                                                short* __restrict__ Vp) {
  const int bid = blockIdx.x;
  if (bid < QK_BLOCKS) {
    const int idx = bid * 256 + threadIdx.x;
    const int kd = idx % 12;
    const int h  = (idx / 12) % 16;
    const int s  = (idx / 192) % S_TOT;
    const int p  = idx / (192 * S_TOT);
    const int seg = s >> 10, tb = (s >> 6) & 15, t = s & 63;
    short* out = (p ? Kp : Qp) +
                 ((size_t)(((seg * 16 + h) * 16 + tb) * 12 + kd) * 64 + t) * 8;
    short tmp[8];
    if (kd >= 10) {
      #pragma unroll
      for (int j = 0; j < 8; ++j) tmp[j] = 0;
      *(int4*)out = *(int4*)tmp;
      return;
    }
    const short* row = (const short*)qkv + (size_t)s * TDIM + p * DIM + h * HD;
    const int d0 = kd * 8;
    const v8s xm = *(const v8s*)(row + d0);
    const v8s xr = *(const v8s*)(row + d0 + ((kd < 5) ? 40 : -40));
    const float sgn = (kd < 5) ? -1.f : 1.f;
    const float scale = (p == 0) ? 0.111803398874989485f : 1.0f;
    #pragma unroll
    for (int j = 0; j < 8; ++j) {
      const int d = d0 + j;
      const float v = (bf2f(xm[j]) * cos_[s * HD + d] +
                       sgn * bf2f(xr[j]) * sin_[s * HD + d]) * scale;
      tmp[j] = f2bf(v);
    }
    *(int4*)out = *(int4*)tmp;
  } else {
    const int idx = (bid - QK_BLOCKS) * 256 + threadIdx.x;
    const int d  = idx % 96;
    const int td = (idx / 96) % 8;
    const int tb = (idx / 768) % 16;
    const int h  = (idx / (768 * 16)) % 16;
    const int seg = idx / (768 * 256);
    const int s0 = seg * SEG + tb * 64 + td * 8;
    const short* q = (const short*)qkv;
    short tmp[8];
    if (d < 80) {
      #pragma unroll
      for (int j = 0; j < 8; ++j)
        tmp[j] = q[(size_t)(s0 + j) * TDIM + 2 * DIM + h * HD + d];
    } else {
      const short fill = (d == 80) ? (short)0x3F80 : (short)0;
      #pragma unroll
      for (int j = 0; j < 8; ++j) tmp[j] = fill;
    }
    *(int4*)(Vp + (size_t)idx * 8) = *(int4*)tmp;
  }
}

// -------- fused flash MFMA attention (r19 XCD group mapping, kept) ----------
__global__ __launch_bounds__(256, 4) void attn_mfma(const short* __restrict__ Qp,
                                                    const short* __restrict__ Kp,
                                                    const short* __restrict__ Vp,
                                                    __hip_bfloat16* __restrict__ out) {
  __shared__ __align__(16) short Ks[64 * 96];
  __shared__ __align__(16) short Vs[64 * 96];
  __shared__ __align__(16) short Ps[4][16 * 68];

  const int l   = blockIdx.x;
  const int xcd = l & 7;
  const int j8  = l >> 3;            // 0..95
  const int g   = xcd * 6 + (j8 >> 4);  // group 0..47  (= seg*16 + h)
  const int qt  = j8 & 15;
  const int h   = g & 15;
  const int seg = g >> 4;
  const int tid  = threadIdx.x;
  const int wave = tid >> 6;
  const int lane = tid & 63;
  const int quad = lane >> 4;
  const int l16  = lane & 15;
  const int sh16 = g;

  const short* Qg = Qp + (size_t)(sh16 * 16 + qt) * 6144;
  const short* Kg = Kp + (size_t)sh16 * 16 * 6144;
  const short* Vg = Vp + (size_t)sh16 * 16 * 6144;

  v8s af[3];
  #pragma unroll
  for (int ks = 0; ks < 3; ++ks)
    af[ks] = *(const v8s*)(Qg + ((ks * 4 + quad) * 64 + wave * 16 + l16) * 8);

  v8s kr[3], vr[3];
  #pragma unroll
  for (int it = 0; it < 3; ++it) {
    const int o = (it * 256 + tid) * 8;
    kr[it] = *(const v8s*)(Kg + o);
    vr[it] = *(const v8s*)(Vg + o);
  }
  #pragma unroll
  for (int it = 0; it < 3; ++it) {
    const int o = (it * 256 + tid) * 8;
    *(v8s*)&Ks[o] = kr[it];
    *(v8s*)&Vs[o] = vr[it];
  }
  __syncthreads();

  v4f o4[6];
  const v4f vz = {0.f, 0.f, 0.f, 0.f};
  #pragma unroll
  for (int n = 0; n < 6; ++n) o4[n] = vz;

  for (int kb = 0; kb < 16; ++kb) {
    const bool more = (kb + 1 < 16);
    if (more) {
      const size_t base = (size_t)(kb + 1) * 6144;
      #pragma unroll
      for (int it = 0; it < 3; ++it) {
        const int o = (it * 256 + tid) * 8;
        kr[it] = *(const v8s*)(Kg + base + o);
        vr[it] = *(const v8s*)(Vg + base + o);
      }
    }

    v4f s4[4];
    #pragma unroll
    for (int j = 0; j < 4; ++j) {
      s4[j] = vz;
      #pragma unroll
      for (int ks = 0; ks < 3; ++ks) {
        const v8s bf = *(const v8s*)&Ks[((ks * 4 + quad) * 64 + j * 16 + l16) * 8];
        s4[j] = __builtin_amdgcn_mfma_f32_16x16x32_bf16(af[ks], bf, s4[j], 0, 0, 0);
      }
    }

    #pragma unroll
    for (int reg = 0; reg < 4; ++reg)
      #pragma unroll
      for (int j = 0; j < 4; ++j)
        Ps[wave][(quad * 4 + reg) * 68 + j * 16 + l16] = f2bf(__expf(s4[j][reg]));

    v8s pa[2];
    #pragma unroll
    for (int kp = 0; kp < 2; ++kp)
      pa[kp] = *(const v8s*)&Ps[wave][l16 * 68 + kp * 32 + quad * 8];
    #pragma unroll
    for (int n = 0; n < 6; ++n) {
      #pragma unroll
      for (int kp = 0; kp < 2; ++kp) {
        const v8s vb = *(const v8s*)&Vs[((kp * 4 + quad) * 96 + n * 16 + l16) * 8];
        o4[n] = __builtin_amdgcn_mfma_f32_16x16x32_bf16(pa[kp], vb, o4[n], 0, 0, 0);
      }
    }

    __syncthreads();
    if (more) {
      #pragma unroll
      for (int it = 0; it < 3; ++it) {
        const int o = (it * 256 + tid) * 8;
        *(v8s*)&Ks[o] = kr[it];
        *(v8s*)&Vs[o] = vr[it];
      }
    }
    __syncthreads();
  }

  float inv[4];
  #pragma unroll
  for (int r = 0; r < 4; ++r)
    inv[r] = 1.f / __shfl(o4[5][r], quad << 4);
  const int row0 = seg * SEG + qt * 64 + wave * 16 + quad * 4;
  #pragma unroll
  for (int n = 0; n < 5; ++n) {
    const int col = h * HD + n * 16 + l16;
    #pragma unroll
    for (int r = 0; r < 4; ++r)
      out[(size_t)(row0 + r) * DIM + col] = __float2bfloat16(o4[n][r] * inv[r]);
  }
}

extern "C" void kernel_launch(void* const* d_in, const int* in_sizes, int n_in,
                              void* d_out, int out_size, void* d_ws, size_t ws_size,
                              hipStream_t stream) {
  (void)in_sizes; (void)n_in; (void)out_size; (void)ws_size;
  const float* hs     = (const float*)d_in[0];
  const float* cosp   = (const float*)d_in[1];
  const float* sinp   = (const float*)d_in[2];
  const float* qkv_w  = (const float*)d_in[3];
  const float* qkv_b  = (const float*)d_in[4];
  const float* proj_w = (const float*)d_in[5];
  const float* proj_b = (const float*)d_in[6];

  float* out_f = (float*)d_out;
  __hip_bfloat16* qkv_b16 = (__hip_bfloat16*)d_ws;                     // [A]
  __hip_bfloat16* hs_b    = qkv_b16 + (size_t)S_TOT * TDIM;            // [B]
  __hip_bfloat16* qkvw_b  = hs_b + (size_t)S_TOT * DIM;                // [C]
  __hip_bfloat16* projw_b = qkvw_b + (size_t)TDIM * DIM;               // [D]
  short* Qp = (short*)qkvw_b;                                          // alias [C]
  short* Kp = (short*)(projw_b + (size_t)DIM * DIM);                   // [E]
  short* Vp = Kp + (size_t)3 * 16 * 16 * 6144;                         // [F]
  __hip_bfloat16* attn_b = hs_b;                                       // alias [B]

  static bool attr_set = false;
  if (!attr_set) {
    hipFuncSetAttribute((const void*)gemm1_3r,
                        hipFuncAttributeMaxDynamicSharedMemorySize, 98304);
    hipFuncSetAttribute((const void*)gemm2_3r,
                        hipFuncAttributeMaxDynamicSharedMemorySize, 49152);
    attr_set = true;
  }

  cvt3<<<(CVT_N1 + CVT_N2 + CVT_N3) / 256, 256, 0, stream>>>(
      hs, qkv_w, proj_w, hs_b, qkvw_b, projw_b);

  gemm1_3r<<<dim3(S_TOT / 256, TDIM / 256), 512, 98304, stream>>>(
      hs_b, qkvw_b, qkv_b, qkv_b16);

  pack_all<<<QK_BLOCKS + V_BLOCKS, 256, 0, stream>>>(qkv_b16, cosp, sinp, Qp, Kp, Vp);

  attn_mfma<<<dim3(768), 256, 0, stream>>>(Qp, Kp, Vp, attn_b);

  gemm2_3r<<<dim3(S_TOT / 128, DIM / 128), 256, 49152, stream>>>(
      attn_b, projw_b, proj_b, out_f);
}

// Round 10
// 202.845 us; speedup vs baseline: 1.0210x; 1.0146x over previous
//
#include <hip/hip_runtime.h>
#include <hip/hip_bf16.h>

// Round 25: gemm1 = r22's proven 3-ring ledger + 4-phase intra-tile interleave.
// r22/r24 measured per-tile ~2500cy vs ~1100cy work floor -> single-barrier
// convoy (all 8 waves burst 12 ds_reads then stall together; MfmaUtil 25%).
// m196/m201: per-phase {ds_read || stage || MFMA} interleave is the lever.
// SAFETY: the 4 added barriers are SCHEDULING-ONLY -- every phase reads tile t
// (fully resident since end-of-(t-1) wait) and stages into buf (t+2)%3 whose
// readers finished at the end-of-(t-1) barrier. Ledger (counted vmcnt(4) +
// 1 real barrier per tile) is bit-identical to r22. Worst case = r22 +
// barrier overhead, cannot corrupt data. Rest identical to r24.
//
// ws layout (r10):
//   [A] qkv_b16: 3072*3840 bf16   [B] hs_b: 3072*1280 bf16 (-> attn_b)
//   [C] qkvw_b : 3840*1280 bf16 (-> Qp)   [D] projw_b: 1280*1280 bf16
//   [E] Kp 9.4MB   [F] Vp 9.4MB (96-wide, col80 = ones)

#define S_TOT 3072
#define DIM   1280
#define NH    16
#define HD    80
#define SEG   1024
#define TDIM  3840
#define K1    1280

typedef short v8s __attribute__((ext_vector_type(8)));
typedef float v4f __attribute__((ext_vector_type(4)));

__device__ __forceinline__ short f2bf(float v) {
  __hip_bfloat16 b = __float2bfloat16(v);
  return *reinterpret_cast<short*>(&b);
}

__device__ __forceinline__ float bf2f(short s) {
  unsigned u = ((unsigned)(unsigned short)s) << 16;
  float f;
  __builtin_memcpy(&f, &u, 4);
  return f;
}

// async global->LDS, 16B per lane, wave-uniform LDS base + lane*16 dest
__device__ __forceinline__ void gload16(const void* g, void* lds) {
  __builtin_amdgcn_global_load_lds(
      (const __attribute__((address_space(1))) char*)g,
      (__attribute__((address_space(3))) char*)lds, 16, 0, 0);
}

#define CVT_N1 (S_TOT * DIM / 4)
#define CVT_N2 (TDIM * DIM / 4)
#define CVT_N3 (DIM * DIM / 4)
__global__ __launch_bounds__(256) void cvt3(const float* __restrict__ in1,
                                            const float* __restrict__ in2,
                                            const float* __restrict__ in3,
                                            __hip_bfloat16* __restrict__ o1,
                                            __hip_bfloat16* __restrict__ o2,
                                            __hip_bfloat16* __restrict__ o3) {
  int i = blockIdx.x * 256 + threadIdx.x;
  const float* in;
  __hip_bfloat16* out;
  if (i < CVT_N1) { in = in1; out = o1; }
  else if (i < CVT_N1 + CVT_N2) { in = in2; out = o2; i -= CVT_N1; }
  else { in = in3; out = o3; i -= CVT_N1 + CVT_N2; }
  const float4 v = ((const float4*)in)[i];
  __hip_bfloat162 p0, p1;
  p0.x = __float2bfloat16(v.x); p0.y = __float2bfloat16(v.y);
  p1.x = __float2bfloat16(v.z); p1.y = __float2bfloat16(v.w);
  __hip_bfloat162* o = (__hip_bfloat162*)(out + (size_t)i * 4);
  o[0] = p0; o[1] = p1;
}

// ====== gemm1_3r: 256x256, BK=32, 3-ring (96KB), 4-phase interleave =========
// LDS buffer b at b*16384 shorts: A region +0 (256 rows), B region +8192.
// Chunk (row,pos): offset (row>>1)*64 + (row&1)*32 + pos*8 shorts; holds
// global k-chunk pos ^ ((row>>1)&3). Staged linearly: chunk ci = c*512 + tid.
extern __shared__ short ring[];

__global__ __launch_bounds__(512, 2) void gemm1_3r(const __hip_bfloat16* __restrict__ A,
                                                   const __hip_bfloat16* __restrict__ B,
                                                   const float* __restrict__ bias,
                                                   __hip_bfloat16* __restrict__ C) {
  const int tid  = threadIdx.x;
  const int wave = tid >> 6;
  const int lane = tid & 63;
  const int quad = lane >> 4;
  const int l16  = lane & 15;
  const int wmp  = wave >> 2;        // 0..1 : wave M-half (128 rows)
  const int wnp  = wave & 3;         // 0..3 : wave N-strip (64 cols)
  const int bm = blockIdx.x * 256;
  const int bn = blockIdx.y * 256;

  // ---- staging source (src-side pre-swizzle; thread's chunk = c*512 + tid) --
  const int r0 = ((tid >> 3) << 1) + ((tid >> 2) & 1);   // row 0..127 in half
  const int gs = (tid & 3) ^ ((tid >> 3) & 3);           // source k-chunk
  const short* A0 = (const short*)A + (size_t)(bm + r0) * K1 + gs * 8;
  const short* A1 = A0 + (size_t)128 * K1;
  const short* B0 = (const short*)B + (size_t)(bn + r0) * K1 + gs * 8;
  const short* B1 = B0 + (size_t)128 * K1;
  const int wst = wave * 512;        // wave-uniform LDS offset (shorts)

#define STG(sbuf, ko) do {                              \
    short* d_ = ring + (sbuf) * 16384;                  \
    gload16(A0 + (ko), d_ + wst);                       \
    gload16(A1 + (ko), d_ + 4096 + wst);                \
    gload16(B0 + (ko), d_ + 8192 + wst);                \
    gload16(B1 + (ko), d_ + 12288 + wst);               \
  } while (0)

  // ---- read-side bases (per-thread constants) ----
  const int posA  = quad ^ ((l16 >> 1) & 3);
  const int rbase = (l16 >> 1) * 64 + (l16 & 1) * 32 + posA * 8;
  const int Abase = wmp * 4096 + rbase;          // + i*512 per 16-row step
  const int Bbase = 8192 + wnp * 2048 + rbase;   // + j*512

  v4f acc[8][4];
  const v4f vz = {0.f, 0.f, 0.f, 0.f};
  #pragma unroll
  for (int i = 0; i < 8; ++i)
    #pragma unroll
    for (int j = 0; j < 4; ++j) acc[i][j] = vz;

  // ---- prologue: stage tiles 0,1; wait for tile 0 only (counted) ----
  STG(0, 0);
  STG(1, 32);
  asm volatile("s_waitcnt vmcnt(4)" ::: "memory");
  __builtin_amdgcn_s_barrier();
  __builtin_amdgcn_sched_barrier(0);

  int cb = 0, sb = 2;                // read buf, stage buf
  for (int t = 0; t < 40; ++t) {
    const short* lb = ring + cb * 16384;
    short* sd = ring + sb * 16384;
    const bool more = (t + 2 < 40);
    const int ko = (t + 2) * 32;
    v8s af[8], bf[4];

    // -- phase 0: read af[0..3], bf[0..1]; stage A0; MFMA (i<4, j<2) --
    #pragma unroll
    for (int i = 0; i < 4; ++i) af[i] = *(const v8s*)&lb[Abase + i * 512];
    #pragma unroll
    for (int j = 0; j < 2; ++j) bf[j] = *(const v8s*)&lb[Bbase + j * 512];
    if (more) gload16(A0 + ko, sd + wst);
    __builtin_amdgcn_s_barrier();
    __builtin_amdgcn_sched_barrier(0);
    __builtin_amdgcn_s_setprio(1);
    #pragma unroll
    for (int i = 0; i < 4; ++i)
      #pragma unroll
      for (int j = 0; j < 2; ++j)
        acc[i][j] = __builtin_amdgcn_mfma_f32_16x16x32_bf16(af[i], bf[j], acc[i][j], 0, 0, 0);
    __builtin_amdgcn_s_setprio(0);
    __builtin_amdgcn_sched_barrier(0);

    // -- phase 1: read af[4..7]; stage A1; MFMA (i>=4, j<2) --
    #pragma unroll
    for (int i = 4; i < 8; ++i) af[i] = *(const v8s*)&lb[Abase + i * 512];
    if (more) gload16(A1 + ko, sd + 4096 + wst);
    __builtin_amdgcn_s_barrier();
    __builtin_amdgcn_sched_barrier(0);
    __builtin_amdgcn_s_setprio(1);
    #pragma unroll
    for (int i = 4; i < 8; ++i)
      #pragma unroll
      for (int j = 0; j < 2; ++j)
        acc[i][j] = __builtin_amdgcn_mfma_f32_16x16x32_bf16(af[i], bf[j], acc[i][j], 0, 0, 0);
    __builtin_amdgcn_s_setprio(0);
    __builtin_amdgcn_sched_barrier(0);

    // -- phase 2: read bf[2..3]; stage B0; MFMA (i>=4, j>=2) --
    #pragma unroll
    for (int j = 2; j < 4; ++j) bf[j] = *(const v8s*)&lb[Bbase + j * 512];
    if (more) gload16(B0 + ko, sd + 8192 + wst);
    __builtin_amdgcn_s_barrier();
    __builtin_amdgcn_sched_barrier(0);
    __builtin_amdgcn_s_setprio(1);
    #pragma unroll
    for (int i = 4; i < 8; ++i)
      #pragma unroll
      for (int j = 2; j < 4; ++j)
        acc[i][j] = __builtin_amdgcn_mfma_f32_16x16x32_bf16(af[i], bf[j], acc[i][j], 0, 0, 0);
    __builtin_amdgcn_s_setprio(0);
    __builtin_amdgcn_sched_barrier(0);

    // -- phase 3: stage B1; MFMA (i<4, j>=2) --
    if (more) gload16(B1 + ko, sd + 12288 + wst);
    __builtin_amdgcn_s_barrier();
    __builtin_amdgcn_sched_barrier(0);
    __builtin_amdgcn_s_setprio(1);
    #pragma unroll
    for (int i = 0; i < 4; ++i)
      #pragma unroll
      for (int j = 2; j < 4; ++j)
        acc[i][j] = __builtin_amdgcn_mfma_f32_16x16x32_bf16(af[i], bf[j], acc[i][j], 0, 0, 0);
    __builtin_amdgcn_s_setprio(0);
    __builtin_amdgcn_sched_barrier(0);

    // -- end-of-tile: counted wait (tile t+1 resident), real barrier --
    if (t < 39) {
      if (more) asm volatile("s_waitcnt vmcnt(4)" ::: "memory");
      else      asm volatile("s_waitcnt vmcnt(0)" ::: "memory");
      __builtin_amdgcn_s_barrier();
      __builtin_amdgcn_sched_barrier(0);
    }
    cb = (cb == 2) ? 0 : cb + 1;
    sb = (sb == 2) ? 0 : sb + 1;
  }
#undef STG

  #pragma unroll
  for (int j = 0; j < 4; ++j) {
    const int col = bn + wnp * 64 + j * 16 + l16;
    const float bj = bias[col];
    #pragma unroll
    for (int i = 0; i < 8; ++i) {
      const int row0 = bm + wmp * 128 + i * 16 + quad * 4;
      #pragma unroll
      for (int r = 0; r < 4; ++r)
        C[(size_t)(row0 + r) * TDIM + col] = __float2bfloat16(acc[i][j][r] + bj);
    }
  }
}

// ===== gemm2_3r: 128x128, BK=32, 3-ring (48KB), counted vmcnt, f32 out =======
__global__ __launch_bounds__(256, 3) void gemm2_3r(const __hip_bfloat16* __restrict__ A,
                                                   const __hip_bfloat16* __restrict__ B,
                                                   const float* __restrict__ bias,
                                                   float* __restrict__ C) {
  const int tid  = threadIdx.x;
  const int wave = tid >> 6;
  const int lane = tid & 63;
  const int quad = lane >> 4;
  const int l16  = lane & 15;
  const int wmp  = wave >> 1;        // 0..1 : wave M-half (64 rows)
  const int wnp  = wave & 1;         // 0..1 : wave N-half (64 cols)
  const int bm = blockIdx.x * 128;
  const int bn = blockIdx.y * 128;

  const int r0 = ((tid >> 3) << 1) + ((tid >> 2) & 1);   // row 0..63
  const int gs = (tid & 3) ^ ((tid >> 3) & 3);           // source k-chunk
  const short* A0 = (const short*)A + (size_t)(bm + r0) * K1 + gs * 8;
  const short* A1 = A0 + (size_t)64 * K1;
  const short* B0 = (const short*)B + (size_t)(bn + r0) * K1 + gs * 8;
  const short* B1 = B0 + (size_t)64 * K1;
  const int wst = wave * 512;

#define STG2(sbuf, ko) do {                             \
    short* d_ = ring + (sbuf) * 8192;                   \
    gload16(A0 + (ko), d_ + wst);                       \
    gload16(A1 + (ko), d_ + 2048 + wst);                \
    gload16(B0 + (ko), d_ + 4096 + wst);                \
    gload16(B1 + (ko), d_ + 6144 + wst);                \
  } while (0)

  const int posA  = quad ^ ((l16 >> 1) & 3);
  const int rbase = (l16 >> 1) * 64 + (l16 & 1) * 32 + posA * 8;
  const int Abase = wmp * 2048 + rbase;
  const int Bbase = 4096 + wnp * 2048 + rbase;

  v4f acc[4][4];
  const v4f vz = {0.f, 0.f, 0.f, 0.f};
  #pragma unroll
  for (int i = 0; i < 4; ++i)
    #pragma unroll
    for (int j = 0; j < 4; ++j) acc[i][j] = vz;

  STG2(0, 0);
  STG2(1, 32);
  asm volatile("s_waitcnt vmcnt(4)" ::: "memory");
  __builtin_amdgcn_s_barrier();
  __builtin_amdgcn_sched_barrier(0);

  int cb = 0, sb = 2;
  for (int t = 0; t < 40; ++t) {
    if (t + 2 < 40) STG2(sb, (t + 2) * 32);

    const short* lb = ring + cb * 8192;
    v8s af[4], bf[4];
    #pragma unroll
    for (int i = 0; i < 4; ++i) af[i] = *(const v8s*)&lb[Abase + i * 512];
    #pragma unroll
    for (int j = 0; j < 4; ++j) bf[j] = *(const v8s*)&lb[Bbase + j * 512];

    __builtin_amdgcn_s_setprio(1);
    #pragma unroll
    for (int i = 0; i < 4; ++i)
      #pragma unroll
      for (int j = 0; j < 4; ++j)
        acc[i][j] = __builtin_amdgcn_mfma_f32_16x16x32_bf16(af[i], bf[j], acc[i][j], 0, 0, 0);
    __builtin_amdgcn_s_setprio(0);

    if (t < 39) {
      if (t + 2 < 40) asm volatile("s_waitcnt vmcnt(4)" ::: "memory");
      else            asm volatile("s_waitcnt vmcnt(0)" ::: "memory");
      __builtin_amdgcn_s_barrier();
      __builtin_amdgcn_sched_barrier(0);
    }
    cb = (cb == 2) ? 0 : cb + 1;
    sb = (sb == 2) ? 0 : sb + 1;
  }
#undef STG2

  #pragma unroll
  for (int j = 0; j < 4; ++j) {
    const int col = bn + wnp * 64 + j * 16 + l16;
    const float bj = bias[col];
    #pragma unroll
    for (int i = 0; i < 4; ++i) {
      const int row0 = bm + wmp * 64 + i * 16 + quad * 4;
      #pragma unroll
      for (int r = 0; r < 4; ++r)
        C[(size_t)(row0 + r) * DIM + col] = acc[i][j][r] + bj;
    }
  }
}

// ---------------- merged pack kernel (unchanged) ----------------
#define QK_BLOCKS ((2 * S_TOT * 16 * 12) / 256)   // 4608
#define V_BLOCKS  ((3 * 16 * 16 * 8 * 96) / 256)  // 2304
__global__ __launch_bounds__(256) void pack_all(const __hip_bfloat16* __restrict__ qkv,
                                                const float* __restrict__ cos_,
                                                const float* __restrict__ sin_,
                                                short* __restrict__ Qp,
                                                short* __restrict__ Kp,
                                                short* __restrict__ Vp) {
  const int bid = blockIdx.x;
  if (bid < QK_BLOCKS) {
    const int idx = bid * 256 + threadIdx.x;
    const int kd = idx % 12;
    const int h  = (idx / 12) % 16;
    const int s  = (idx / 192) % S_TOT;
    const int p  = idx / (192 * S_TOT);
    const int seg = s >> 10, tb = (s >> 6) & 15, t = s & 63;
    short* out = (p ? Kp : Qp) +
                 ((size_t)(((seg * 16 + h) * 16 + tb) * 12 + kd) * 64 + t) * 8;
    short tmp[8];
    if (kd >= 10) {
      #pragma unroll
      for (int j = 0; j < 8; ++j) tmp[j] = 0;
      *(int4*)out = *(int4*)tmp;
      return;
    }
    const short* row = (const short*)qkv + (size_t)s * TDIM + p * DIM + h * HD;
    const int d0 = kd * 8;
    const v8s xm = *(const v8s*)(row + d0);
    const v8s xr = *(const v8s*)(row + d0 + ((kd < 5) ? 40 : -40));
    const float sgn = (kd < 5) ? -1.f : 1.f;
    const float scale = (p == 0) ? 0.111803398874989485f : 1.0f;
    #pragma unroll
    for (int j = 0; j < 8; ++j) {
      const int d = d0 + j;
      const float v = (bf2f(xm[j]) * cos_[s * HD + d] +
                       sgn * bf2f(xr[j]) * sin_[s * HD + d]) * scale;
      tmp[j] = f2bf(v);
    }
    *(int4*)out = *(int4*)tmp;
  } else {
    const int idx = (bid - QK_BLOCKS) * 256 + threadIdx.x;
    const int d  = idx % 96;
    const int td = (idx / 96) % 8;
    const int tb = (idx / 768) % 16;
    const int h  = (idx / (768 * 16)) % 16;
    const int seg = idx / (768 * 256);
    const int s0 = seg * SEG + tb * 64 + td * 8;
    const short* q = (const short*)qkv;
    short tmp[8];
    if (d < 80) {
      #pragma unroll
      for (int j = 0; j < 8; ++j)
        tmp[j] = q[(size_t)(s0 + j) * TDIM + 2 * DIM + h * HD + d];
    } else {
      const short fill = (d == 80) ? (short)0x3F80 : (short)0;
      #pragma unroll
      for (int j = 0; j < 8; ++j) tmp[j] = fill;
    }
    *(int4*)(Vp + (size_t)idx * 8) = *(int4*)tmp;
  }
}

// -------- fused flash MFMA attention (r19 XCD group mapping, kept) ----------
__global__ __launch_bounds__(256, 4) void attn_mfma(const short* __restrict__ Qp,
                                                    const short* __restrict__ Kp,
                                                    const short* __restrict__ Vp,
                                                    __hip_bfloat16* __restrict__ out) {
  __shared__ __align__(16) short Ks[64 * 96];
  __shared__ __align__(16) short Vs[64 * 96];
  __shared__ __align__(16) short Ps[4][16 * 68];

  const int l   = blockIdx.x;
  const int xcd = l & 7;
  const int j8  = l >> 3;            // 0..95
  const int g   = xcd * 6 + (j8 >> 4);  // group 0..47  (= seg*16 + h)
  const int qt  = j8 & 15;
  const int h   = g & 15;
  const int seg = g >> 4;
  const int tid  = threadIdx.x;
  const int wave = tid >> 6;
  const int lane = tid & 63;
  const int quad = lane >> 4;
  const int l16  = lane & 15;
  const int sh16 = g;

  const short* Qg = Qp + (size_t)(sh16 * 16 + qt) * 6144;
  const short* Kg = Kp + (size_t)sh16 * 16 * 6144;
  const short* Vg = Vp + (size_t)sh16 * 16 * 6144;

  v8s af[3];
  #pragma unroll
  for (int ks = 0; ks < 3; ++ks)
    af[ks] = *(const v8s*)(Qg + ((ks * 4 + quad) * 64 + wave * 16 + l16) * 8);

  v8s kr[3], vr[3];
  #pragma unroll
  for (int it = 0; it < 3; ++it) {
    const int o = (it * 256 + tid) * 8;
    kr[it] = *(const v8s*)(Kg + o);
    vr[it] = *(const v8s*)(Vg + o);
  }
  #pragma unroll
  for (int it = 0; it < 3; ++it) {
    const int o = (it * 256 + tid) * 8;
    *(v8s*)&Ks[o] = kr[it];
    *(v8s*)&Vs[o] = vr[it];
  }
  __syncthreads();

  v4f o4[6];
  const v4f vz = {0.f, 0.f, 0.f, 0.f};
  #pragma unroll
  for (int n = 0; n < 6; ++n) o4[n] = vz;

  for (int kb = 0; kb < 16; ++kb) {
    const bool more = (kb + 1 < 16);
    if (more) {
      const size_t base = (size_t)(kb + 1) * 6144;
      #pragma unroll
      for (int it = 0; it < 3; ++it) {
        const int o = (it * 256 + tid) * 8;
        kr[it] = *(const v8s*)(Kg + base + o);
        vr[it] = *(const v8s*)(Vg + base + o);
      }
    }

    v4f s4[4];
    #pragma unroll
    for (int j = 0; j < 4; ++j) {
      s4[j] = vz;
      #pragma unroll
      for (int ks = 0; ks < 3; ++ks) {
        const v8s bf = *(const v8s*)&Ks[((ks * 4 + quad) * 64 + j * 16 + l16) * 8];
        s4[j] = __builtin_amdgcn_mfma_f32_16x16x32_bf16(af[ks], bf, s4[j], 0, 0, 0);
      }
    }

    #pragma unroll
    for (int reg = 0; reg < 4; ++reg)
      #pragma unroll
      for (int j = 0; j < 4; ++j)
        Ps[wave][(quad * 4 + reg) * 68 + j * 16 + l16] = f2bf(__expf(s4[j][reg]));

    v8s pa[2];
    #pragma unroll
    for (int kp = 0; kp < 2; ++kp)
      pa[kp] = *(const v8s*)&Ps[wave][l16 * 68 + kp * 32 + quad * 8];
    #pragma unroll
    for (int n = 0; n < 6; ++n) {
      #pragma unroll
      for (int kp = 0; kp < 2; ++kp) {
        const v8s vb = *(const v8s*)&Vs[((kp * 4 + quad) * 96 + n * 16 + l16) * 8];
        o4[n] = __builtin_amdgcn_mfma_f32_16x16x32_bf16(pa[kp], vb, o4[n], 0, 0, 0);
      }
    }

    __syncthreads();
    if (more) {
      #pragma unroll
      for (int it = 0; it < 3; ++it) {
        const int o = (it * 256 + tid) * 8;
        *(v8s*)&Ks[o] = kr[it];
        *(v8s*)&Vs[o] = vr[it];
      }
    }
    __syncthreads();
  }

  float inv[4];
  #pragma unroll
  for (int r = 0; r < 4; ++r)
    inv[r] = 1.f / __shfl(o4[5][r], quad << 4);
  const int row0 = seg * SEG + qt * 64 + wave * 16 + quad * 4;
  #pragma unroll
  for (int n = 0; n < 5; ++n) {
    const int col = h * HD + n * 16 + l16;
    #pragma unroll
    for (int r = 0; r < 4; ++r)
      out[(size_t)(row0 + r) * DIM + col] = __float2bfloat16(o4[n][r] * inv[r]);
  }
}

extern "C" void kernel_launch(void* const* d_in, const int* in_sizes, int n_in,
                              void* d_out, int out_size, void* d_ws, size_t ws_size,
                              hipStream_t stream) {
  (void)in_sizes; (void)n_in; (void)out_size; (void)ws_size;
  const float* hs     = (const float*)d_in[0];
  const float* cosp   = (const float*)d_in[1];
  const float* sinp   = (const float*)d_in[2];
  const float* qkv_w  = (const float*)d_in[3];
  const float* qkv_b  = (const float*)d_in[4];
  const float* proj_w = (const float*)d_in[5];
  const float* proj_b = (const float*)d_in[6];

  float* out_f = (float*)d_out;
  __hip_bfloat16* qkv_b16 = (__hip_bfloat16*)d_ws;                     // [A]
  __hip_bfloat16* hs_b    = qkv_b16 + (size_t)S_TOT * TDIM;            // [B]
  __hip_bfloat16* qkvw_b  = hs_b + (size_t)S_TOT * DIM;                // [C]
  __hip_bfloat16* projw_b = qkvw_b + (size_t)TDIM * DIM;               // [D]
  short* Qp = (short*)qkvw_b;                                          // alias [C]
  short* Kp = (short*)(projw_b + (size_t)DIM * DIM);                   // [E]
  short* Vp = Kp + (size_t)3 * 16 * 16 * 6144;                         // [F]
  __hip_bfloat16* attn_b = hs_b;                                       // alias [B]

  static bool attr_set = false;
  if (!attr_set) {
    hipFuncSetAttribute((const void*)gemm1_3r,
                        hipFuncAttributeMaxDynamicSharedMemorySize, 98304);
    hipFuncSetAttribute((const void*)gemm2_3r,
                        hipFuncAttributeMaxDynamicSharedMemorySize, 49152);
    attr_set = true;
  }

  cvt3<<<(CVT_N1 + CVT_N2 + CVT_N3) / 256, 256, 0, stream>>>(
      hs, qkv_w, proj_w, hs_b, qkvw_b, projw_b);

  gemm1_3r<<<dim3(S_TOT / 256, TDIM / 256), 512, 98304, stream>>>(
      hs_b, qkvw_b, qkv_b, qkv_b16);

  pack_all<<<QK_BLOCKS + V_BLOCKS, 256, 0, stream>>>(qkv_b16, cosp, sinp, Qp, Kp, Vp);

  attn_mfma<<<dim3(768), 256, 0, stream>>>(Qp, Kp, Vp, attn_b);

  gemm2_3r<<<dim3(S_TOT / 128, DIM / 128), 256, 49152, stream>>>(
      attn_b, projw_b, proj_b, out_f);
}